// Round 1
// baseline (920.253 us; speedup 1.0000x reference)
//
#include <hip/hip_runtime.h>
#include <hip/hip_bf16.h>
#include <cstdint>
#include <cstddef>

// ---------- types ----------
typedef __attribute__((ext_vector_type(8))) short short8;   // bf16 x8 (4 VGPRs)
typedef __attribute__((ext_vector_type(4))) short short4v;  // bf16 x4
typedef __attribute__((ext_vector_type(4))) float floatx4;

#define D_MODEL 512
#define HDIM    2048
#define TSEQ    16384
#define NTOK    65536   // B*T = 4*16384

// ---------- helpers ----------
__device__ __forceinline__ float bf2f(short s) {
  union { unsigned u; float f; } v; v.u = ((unsigned)(unsigned short)s) << 16; return v.f;
}
__device__ __forceinline__ short f2bf(float f) {
  union { float fv; unsigned u; } v; v.fv = f;
  unsigned u = v.u;
  u += 0x7FFFu + ((u >> 16) & 1u);   // RNE
  return (short)(u >> 16);
}
__device__ __forceinline__ void gload_lds16(const void* g, void* l) {
  // width=16 async global->LDS; LDS dest = wave-uniform base + lane*16 (m104)
  __builtin_amdgcn_global_load_lds((const __attribute__((address_space(1))) void*)g,
                                   (__attribute__((address_space(3))) void*)l, 16, 0, 0);
}

// ---------- weight convert + transpose: W[K][N] f32 -> Wt[N][K] bf16 ----------
__global__ void wt_transpose(const float* __restrict__ W, short* __restrict__ Wt,
                             const int K, const int N) {
  __shared__ float t[64][65];
  const int tid = threadIdx.x;
  const long k0 = (long)blockIdx.x * 64;
  const long n0 = (long)blockIdx.y * 64;
  const int rr = tid >> 4;
  const int cc = (tid & 15) * 4;
#pragma unroll
  for (int i = 0; i < 4; ++i) {
    const int r = rr + i * 16;
    const float4 v = *(const float4*)(W + (k0 + r) * N + n0 + cc);
    t[r][cc + 0] = v.x; t[r][cc + 1] = v.y; t[r][cc + 2] = v.z; t[r][cc + 3] = v.w;
  }
  __syncthreads();
#pragma unroll
  for (int i = 0; i < 4; ++i) {
    const int n = rr + i * 16;
    short4v o;
    o[0] = f2bf(t[cc + 0][n]);
    o[1] = f2bf(t[cc + 1][n]);
    o[2] = f2bf(t[cc + 2][n]);
    o[3] = f2bf(t[cc + 3][n]);
    *(short4v*)(Wt + (n0 + n) * K + k0 + cc) = o;
  }
}

// conv_w [512][17] f32 -> wT [17][512] f32
__global__ void convw_transpose(const float* __restrict__ cw, float* __restrict__ wT) {
  const int idx = blockIdx.x * 256 + threadIdx.x;
  if (idx >= 17 * D_MODEL) return;
  const int k = idx / D_MODEL;
  const int c = idx % D_MODEL;
  wT[idx] = cw[c * 17 + k];
}

// ---------- RMSNorm: one wave per row, f32 in -> bf16 out ----------
__global__ void rmsnorm_kernel(const float* __restrict__ x, const float* __restrict__ w,
                               short* __restrict__ outp) {
  const int lane = threadIdx.x & 63;
  const long row = (long)blockIdx.x * 4 + (threadIdx.x >> 6);
  const float* xr = x + row * D_MODEL + lane * 8;
  const float4 a = *(const float4*)xr;
  const float4 b = *(const float4*)(xr + 4);
  float ss = a.x * a.x + a.y * a.y + a.z * a.z + a.w * a.w
           + b.x * b.x + b.y * b.y + b.z * b.z + b.w * b.w;
#pragma unroll
  for (int m = 32; m; m >>= 1) ss += __shfl_xor(ss, m);
  const float scale = rsqrtf(ss * (1.0f / D_MODEL) + 1e-6f);
  const float4 wa = *(const float4*)(w + lane * 8);
  const float4 wb = *(const float4*)(w + lane * 8 + 4);
  short8 o;
  o[0] = f2bf(a.x * scale * wa.x);
  o[1] = f2bf(a.y * scale * wa.y);
  o[2] = f2bf(a.z * scale * wa.z);
  o[3] = f2bf(a.w * scale * wa.w);
  o[4] = f2bf(b.x * scale * wb.x);
  o[5] = f2bf(b.y * scale * wb.y);
  o[6] = f2bf(b.z * scale * wb.z);
  o[7] = f2bf(b.w * scale * wb.w);
  *(short8*)(outp + row * D_MODEL + lane * 8) = o;
}

// ---------- causal depthwise conv (K=17, dilation=1), bf16 in/out ----------
__global__ void dwconv_kernel(const short* __restrict__ hn, const float* __restrict__ wT,
                              short* __restrict__ hc) {
  const int tid = threadIdx.x;
  const int chunk = tid & 63;                       // 64 chunks of 8 channels
  const long row = (long)blockIdx.x * 4 + (tid >> 6);
  const int t = (int)(row & (TSEQ - 1));
  const int c0 = chunk * 8;
  float acc[8];
#pragma unroll
  for (int j = 0; j < 8; ++j) acc[j] = 0.f;
  const int kmin = (t >= 16) ? 0 : (16 - t);
  for (int k = kmin; k < 17; ++k) {
    const short8 h = *(const short8*)(hn + (row - 16 + k) * D_MODEL + c0);
    const float* wp = wT + k * D_MODEL + c0;
    const float4 w0 = *(const float4*)(wp);
    const float4 w1 = *(const float4*)(wp + 4);
    acc[0] += bf2f(h[0]) * w0.x;
    acc[1] += bf2f(h[1]) * w0.y;
    acc[2] += bf2f(h[2]) * w0.z;
    acc[3] += bf2f(h[3]) * w0.w;
    acc[4] += bf2f(h[4]) * w1.x;
    acc[5] += bf2f(h[5]) * w1.y;
    acc[6] += bf2f(h[6]) * w1.z;
    acc[7] += bf2f(h[7]) * w1.w;
  }
  short8 o;
#pragma unroll
  for (int j = 0; j < 8; ++j) o[j] = f2bf(acc[j]);
  *(short8*)(hc + row * D_MODEL + c0) = o;
}

// ---------- GEMM: C[M][N] = A[M][K](bf16) x Bt[N][K](bf16), fused epilogues ----------
// EPI 0: u = sigmoid(acc) * hc   (aux=hc bf16, outp=u bf16; in-place on hc OK)
// EPI 1: out = x + acc           (aux=x f32,  outp=f32)
// EPI 2: out = gelu_tanh(acc)    (outp=bf16)
// EPI 3: out += acc              (outp=f32, read-modify-write)
template <int EPI>
__global__ __launch_bounds__(256)
void gemm_bt(const short* __restrict__ A, const short* __restrict__ Bt,
             const int K, const int N,
             const void* __restrict__ aux, void* __restrict__ outp) {
  __shared__ short As[128 * 64];
  __shared__ short Bs[128 * 64];
  const int tid = threadIdx.x;
  const int lane = tid & 63;
  const int w = tid >> 6;
  const long brow = (long)blockIdx.x * 128;
  const long bcol = (long)blockIdx.y * 128;

  const floatx4 zero = {0.f, 0.f, 0.f, 0.f};
  floatx4 acc[4][4];
#pragma unroll
  for (int i = 0; i < 4; ++i)
#pragma unroll
    for (int j = 0; j < 4; ++j) acc[i][j] = zero;

  const int wr = (w >> 1) * 64;
  const int wc = (w & 1) * 64;

  // staging: each wave loads 8 rows per instr (16B/lane), 4 instrs each for A and B.
  // source chunk pre-swizzled (chunk ^ (row&7)) so linear LDS dest + swizzled read
  // are conflict-free (both-sides-or-neither rule, m173/m231).
  const int lrow = w * 32 + (lane >> 3);
  const int chunkx = (lane & 7) ^ (lane >> 3);   // (lane&7) ^ (rowL & 7)
  const short* gA = A + (brow + lrow) * (long)K + chunkx * 8;
  const short* gB = Bt + (bcol + lrow) * (long)K + chunkx * 8;
  short* lA = As + (w * 32) * 64;
  short* lB = Bs + (w * 32) * 64;

  for (int kt = 0; kt < K; kt += 64) {
    __syncthreads();
#pragma unroll
    for (int i = 0; i < 4; ++i) {
      gload_lds16(gA + (long)i * 8 * K + kt, lA + i * 8 * 64);
      gload_lds16(gB + (long)i * 8 * K + kt, lB + i * 8 * 64);
    }
    __syncthreads();   // compiler emits vmcnt(0) drain before s_barrier
#pragma unroll
    for (int km = 0; km < 2; ++km) {
      short8 af[4], bfr[4];
#pragma unroll
      for (int mi = 0; mi < 4; ++mi) {
        const int row = wr + mi * 16 + (lane & 15);
        const int ch = (km * 4 + (lane >> 4)) ^ (row & 7);
        af[mi] = *(const short8*)(As + row * 64 + ch * 8);
      }
#pragma unroll
      for (int ni = 0; ni < 4; ++ni) {
        const int row = wc + ni * 16 + (lane & 15);
        const int ch = (km * 4 + (lane >> 4)) ^ (row & 7);
        bfr[ni] = *(const short8*)(Bs + row * 64 + ch * 8);
      }
#pragma unroll
      for (int mi = 0; mi < 4; ++mi)
#pragma unroll
        for (int ni = 0; ni < 4; ++ni)
          acc[mi][ni] = __builtin_amdgcn_mfma_f32_16x16x32_bf16(af[mi], bfr[ni], acc[mi][ni], 0, 0, 0);
    }
  }

  // epilogue: C/D layout col=lane&15, row=(lane>>4)*4+j (m89/m91 verified)
#pragma unroll
  for (int mi = 0; mi < 4; ++mi) {
#pragma unroll
    for (int ni = 0; ni < 4; ++ni) {
      const long gc = bcol + wc + ni * 16 + (lane & 15);
      const long r0 = brow + wr + mi * 16 + (lane >> 4) * 4;
#pragma unroll
      for (int j = 0; j < 4; ++j) {
        const long r = r0 + j;
        const float v = acc[mi][ni][j];
        const long idx = r * (long)N + gc;
        if (EPI == 0) {
          const float hcv = bf2f(((const short*)aux)[idx]);
          const float g = 1.f / (1.f + __expf(-v));
          ((short*)outp)[idx] = f2bf(g * hcv);
        } else if (EPI == 1) {
          ((float*)outp)[idx] = ((const float*)aux)[idx] + v;
        } else if (EPI == 2) {
          const float x3 = v * v * v;
          const float z = 0.7978845608028654f * (v + 0.044715f * x3);
          const float th = 1.f - 2.f / (__expf(2.f * z) + 1.f);   // tanh(z)
          ((short*)outp)[idx] = f2bf(0.5f * v * (1.f + th));
        } else {
          ((float*)outp)[idx] += v;
        }
      }
    }
  }
}

// ---------- launch ----------
extern "C" void kernel_launch(void* const* d_in, const int* in_sizes, int n_in,
                              void* d_out, int out_size, void* d_ws, size_t ws_size,
                              hipStream_t stream) {
  const float* x      = (const float*)d_in[0];
  const float* ln1_w  = (const float*)d_in[1];
  const float* gate_w = (const float*)d_in[2];   // [512][512]
  const float* conv_w = (const float*)d_in[3];   // [512][17]
  const float* proj_w = (const float*)d_in[4];   // [512][512]
  const float* ln2_w  = (const float*)d_in[5];
  const float* mlp_w1 = (const float*)d_in[6];   // [512][2048]
  const float* mlp_w2 = (const float*)d_in[7];   // [2048][512]
  float* out = (float*)d_out;
  char* ws = (char*)d_ws;

  // workspace layout (bytes), all offsets 256B-aligned
  short* hn      = (short*)(ws + 0);                       // 64 MiB  (also hn2 later)
  short* hc      = (short*)(ws + 67108864L);               // 64 MiB  (hc, then u in-place)
  short* mid     = (short*)(ws + 134217728L);              // 256 MiB
  short* gate_wt = (short*)(ws + 402653184L);              // 512 KiB [512][512]
  short* proj_wt = (short*)(ws + 403177472L);              // 512 KiB
  short* w1t     = (short*)(ws + 403701760L);              // 2 MiB   [2048][512]
  short* w2t     = (short*)(ws + 405798912L);              // 2 MiB   [512][2048]
  float* convwT  = (float*)(ws + 407896064L);              // 34 KiB  [17][512]

  const dim3 b256(256);

  // weights -> bf16 transposed (per-call; deterministic, ~5 MB)
  wt_transpose<<<dim3(8, 8),  b256, 0, stream>>>(gate_w, gate_wt, 512, 512);
  wt_transpose<<<dim3(8, 8),  b256, 0, stream>>>(proj_w, proj_wt, 512, 512);
  wt_transpose<<<dim3(8, 32), b256, 0, stream>>>(mlp_w1, w1t, 512, 2048);
  wt_transpose<<<dim3(32, 8), b256, 0, stream>>>(mlp_w2, w2t, 2048, 512);
  convw_transpose<<<34, b256, 0, stream>>>(conv_w, convwT);

  // 1) hn = rmsnorm(x, ln1_w)
  rmsnorm_kernel<<<NTOK / 4, b256, 0, stream>>>(x, ln1_w, hn);
  // 2) hc = causal_dwconv(hn)
  dwconv_kernel<<<NTOK / 4, b256, 0, stream>>>(hn, convwT, hc);
  // 3) u = sigmoid(hn @ gate_w) * hc   (in-place into hc)
  gemm_bt<0><<<dim3(NTOK / 128, 4), b256, 0, stream>>>(hn, gate_wt, 512, 512, hc, hc);
  // 4) x2 = x + u @ proj_w  -> d_out (f32)
  gemm_bt<1><<<dim3(NTOK / 128, 4), b256, 0, stream>>>(hc, proj_wt, 512, 512, x, out);
  // 5) hn2 = rmsnorm(x2, ln2_w)  (reuse hn buffer)
  rmsnorm_kernel<<<NTOK / 4, b256, 0, stream>>>(out, ln2_w, hn);
  // 6) mid = gelu(hn2 @ mlp_w1)
  gemm_bt<2><<<dim3(NTOK / 128, 16), b256, 0, stream>>>(hn, w1t, 512, 2048, nullptr, mid);
  // 7) out += mid @ mlp_w2
  gemm_bt<3><<<dim3(NTOK / 128, 4), b256, 0, stream>>>(mid, w2t, 2048, 512, nullptr, out);
}

// Round 2
// 905.999 us; speedup vs baseline: 1.0157x; 1.0157x over previous
//
#include <hip/hip_runtime.h>
#include <hip/hip_bf16.h>
#include <cstdint>
#include <cstddef>

// ---------- types ----------
typedef __attribute__((ext_vector_type(8))) short short8;   // bf16 x8 (4 VGPRs)
typedef __attribute__((ext_vector_type(4))) short short4v;  // bf16 x4
typedef __attribute__((ext_vector_type(4))) float floatx4;

#define D_MODEL 512
#define HDIM    2048
#define TSEQ    16384
#define NTOK    65536   // B*T = 4*16384

// ---------- helpers ----------
__device__ __forceinline__ float bf2f(short s) {
  union { unsigned u; float f; } v; v.u = ((unsigned)(unsigned short)s) << 16; return v.f;
}
__device__ __forceinline__ short f2bf(float f) {
  union { float fv; unsigned u; } v; v.fv = f;
  unsigned u = v.u;
  u += 0x7FFFu + ((u >> 16) & 1u);   // RNE
  return (short)(u >> 16);
}
__device__ __forceinline__ void gload_lds16(const void* g, void* l) {
  // width=16 async global->LDS; LDS dest = wave-uniform base + lane*16 (m104)
  __builtin_amdgcn_global_load_lds((const __attribute__((address_space(1))) void*)g,
                                   (__attribute__((address_space(3))) void*)l, 16, 0, 0);
}

// ---------- weight convert + transpose: W[K][N] f32 -> Wt[N][K] bf16 ----------
__global__ void wt_transpose(const float* __restrict__ W, short* __restrict__ Wt,
                             const int K, const int N) {
  __shared__ float t[64][65];
  const int tid = threadIdx.x;
  const long k0 = (long)blockIdx.x * 64;
  const long n0 = (long)blockIdx.y * 64;
  const int rr = tid >> 4;
  const int cc = (tid & 15) * 4;
#pragma unroll
  for (int i = 0; i < 4; ++i) {
    const int r = rr + i * 16;
    const float4 v = *(const float4*)(W + (k0 + r) * N + n0 + cc);
    t[r][cc + 0] = v.x; t[r][cc + 1] = v.y; t[r][cc + 2] = v.z; t[r][cc + 3] = v.w;
  }
  __syncthreads();
#pragma unroll
  for (int i = 0; i < 4; ++i) {
    const int n = rr + i * 16;
    short4v o;
    o[0] = f2bf(t[cc + 0][n]);
    o[1] = f2bf(t[cc + 1][n]);
    o[2] = f2bf(t[cc + 2][n]);
    o[3] = f2bf(t[cc + 3][n]);
    *(short4v*)(Wt + (n0 + n) * K + k0 + cc) = o;
  }
}

// conv_w [512][17] f32 -> wT [17][512] f32
__global__ void convw_transpose(const float* __restrict__ cw, float* __restrict__ wT) {
  const int idx = blockIdx.x * 256 + threadIdx.x;
  if (idx >= 17 * D_MODEL) return;
  const int k = idx / D_MODEL;
  const int c = idx % D_MODEL;
  wT[idx] = cw[c * 17 + k];
}

// ---------- RMSNorm: one wave per row, f32 in -> bf16 out ----------
__global__ void rmsnorm_kernel(const float* __restrict__ x, const float* __restrict__ w,
                               short* __restrict__ outp) {
  const int lane = threadIdx.x & 63;
  const long row = (long)blockIdx.x * 4 + (threadIdx.x >> 6);
  const float* xr = x + row * D_MODEL + lane * 8;
  const float4 a = *(const float4*)xr;
  const float4 b = *(const float4*)(xr + 4);
  float ss = a.x * a.x + a.y * a.y + a.z * a.z + a.w * a.w
           + b.x * b.x + b.y * b.y + b.z * b.z + b.w * b.w;
#pragma unroll
  for (int m = 32; m; m >>= 1) ss += __shfl_xor(ss, m);
  const float scale = rsqrtf(ss * (1.0f / D_MODEL) + 1e-6f);
  const float4 wa = *(const float4*)(w + lane * 8);
  const float4 wb = *(const float4*)(w + lane * 8 + 4);
  short8 o;
  o[0] = f2bf(a.x * scale * wa.x);
  o[1] = f2bf(a.y * scale * wa.y);
  o[2] = f2bf(a.z * scale * wa.z);
  o[3] = f2bf(a.w * scale * wa.w);
  o[4] = f2bf(b.x * scale * wb.x);
  o[5] = f2bf(b.y * scale * wb.y);
  o[6] = f2bf(b.z * scale * wb.z);
  o[7] = f2bf(b.w * scale * wb.w);
  *(short8*)(outp + row * D_MODEL + lane * 8) = o;
}

// ---------- causal depthwise conv (K=17, dilation=1), bf16 in/out ----------
__global__ void dwconv_kernel(const short* __restrict__ hn, const float* __restrict__ wT,
                              short* __restrict__ hc) {
  const int tid = threadIdx.x;
  const int chunk = tid & 63;                       // 64 chunks of 8 channels
  const long row = (long)blockIdx.x * 4 + (tid >> 6);
  const int t = (int)(row & (TSEQ - 1));
  const int c0 = chunk * 8;
  float acc[8];
#pragma unroll
  for (int j = 0; j < 8; ++j) acc[j] = 0.f;
  const int kmin = (t >= 16) ? 0 : (16 - t);
  for (int k = kmin; k < 17; ++k) {
    const short8 h = *(const short8*)(hn + (row - 16 + k) * D_MODEL + c0);
    const float* wp = wT + k * D_MODEL + c0;
    const float4 w0 = *(const float4*)(wp);
    const float4 w1 = *(const float4*)(wp + 4);
    acc[0] += bf2f(h[0]) * w0.x;
    acc[1] += bf2f(h[1]) * w0.y;
    acc[2] += bf2f(h[2]) * w0.z;
    acc[3] += bf2f(h[3]) * w0.w;
    acc[4] += bf2f(h[4]) * w1.x;
    acc[5] += bf2f(h[5]) * w1.y;
    acc[6] += bf2f(h[6]) * w1.z;
    acc[7] += bf2f(h[7]) * w1.w;
  }
  short8 o;
#pragma unroll
  for (int j = 0; j < 8; ++j) o[j] = f2bf(acc[j]);
  *(short8*)(hc + row * D_MODEL + c0) = o;
}

// ---------- GEMM: C[M][N] = A[M][K](bf16) x Bt[N][K](bf16), fused epilogues ----------
// 2-phase double-buffered K-loop (T3 minimum): STAGE(next) issued BEFORE compute(cur),
// single __syncthreads() per K-tile (vmcnt drain lands after the MFMAs).
// 1-D grid, N-block fastest, XCD-chunked swizzle (requires gridDim.x % 8 == 0).
// EPI 0: u = sigmoid(acc) * hc   (aux=hc bf16, outp=u bf16; in-place on hc OK)
// EPI 1: out = x + acc           (aux=x f32,  outp=f32)
// EPI 2: out = gelu_tanh(acc)    (outp=bf16)
// EPI 3: out += acc              (outp=f32, read-modify-write)
template <int EPI>
__global__ __launch_bounds__(256, 2)
void gemm_bt(const short* __restrict__ A, const short* __restrict__ Bt,
             const int K, const int N, const int nbn,
             const void* __restrict__ aux, void* __restrict__ outp) {
  __shared__ short As[2][128 * 64];
  __shared__ short Bs[2][128 * 64];
  const int tid = threadIdx.x;
  const int lane = tid & 63;
  const int w = tid >> 6;

  // XCD-chunked swizzle: launch-slot bid -> work-id wid so that each XCD owns a
  // contiguous chunk of work-ids; consecutive wids share the A-panel (nb fastest).
  const int nwg = gridDim.x;
  const int cpx = nwg >> 3;
  const int bid = blockIdx.x;
  const int wid = (bid & 7) * cpx + (bid >> 3);
  const long brow = (long)(wid / nbn) * 128;
  const long bcol = (long)(wid % nbn) * 128;

  const floatx4 zero = {0.f, 0.f, 0.f, 0.f};
  floatx4 acc[4][4];
#pragma unroll
  for (int i = 0; i < 4; ++i)
#pragma unroll
    for (int j = 0; j < 4; ++j) acc[i][j] = zero;

  const int wr = (w >> 1) * 64;
  const int wc = (w & 1) * 64;

  // staging: each wave loads 8 rows per instr (16B/lane), 4 instrs each for A and B.
  // source chunk pre-swizzled (chunk ^ (row&7)) so linear LDS dest + swizzled read
  // are conflict-free (both-sides-or-neither rule, m173/m231).
  const int lrow = w * 32 + (lane >> 3);
  const int chunkx = (lane & 7) ^ (lane >> 3);   // (lane&7) ^ (rowL & 7)
  const short* gA = A + (brow + lrow) * (long)K + chunkx * 8;
  const short* gB = Bt + (bcol + lrow) * (long)K + chunkx * 8;

#define STAGE(buf, ktoff)                                                     \
  {                                                                           \
    _Pragma("unroll")                                                         \
    for (int i = 0; i < 4; ++i) {                                             \
      gload_lds16(gA + (long)i * 8 * K + (ktoff), &As[buf][(w * 32 + i * 8) * 64]); \
      gload_lds16(gB + (long)i * 8 * K + (ktoff), &Bs[buf][(w * 32 + i * 8) * 64]); \
    }                                                                         \
  }

#define COMPUTE(buf)                                                          \
  {                                                                           \
    _Pragma("unroll")                                                         \
    for (int km = 0; km < 2; ++km) {                                          \
      short8 af[4], bfr[4];                                                   \
      _Pragma("unroll")                                                       \
      for (int mi = 0; mi < 4; ++mi) {                                        \
        const int row = wr + mi * 16 + (lane & 15);                           \
        const int ch = (km * 4 + (lane >> 4)) ^ (row & 7);                    \
        af[mi] = *(const short8*)(&As[buf][row * 64 + ch * 8]);               \
      }                                                                       \
      _Pragma("unroll")                                                       \
      for (int ni = 0; ni < 4; ++ni) {                                        \
        const int row = wc + ni * 16 + (lane & 15);                           \
        const int ch = (km * 4 + (lane >> 4)) ^ (row & 7);                    \
        bfr[ni] = *(const short8*)(&Bs[buf][row * 64 + ch * 8]);              \
      }                                                                       \
      _Pragma("unroll")                                                       \
      for (int mi = 0; mi < 4; ++mi)                                          \
        _Pragma("unroll")                                                     \
        for (int ni = 0; ni < 4; ++ni)                                        \
          acc[mi][ni] = __builtin_amdgcn_mfma_f32_16x16x32_bf16(af[mi], bfr[ni], acc[mi][ni], 0, 0, 0); \
    }                                                                         \
  }

  // prologue
  STAGE(0, 0);
  __syncthreads();

  const int nkt = K >> 6;          // K % 128 == 0 for all call sites -> nkt even
  for (int kt = 0; kt < nkt; kt += 2) {
    if (kt + 1 < nkt) STAGE(1, (kt + 1) * 64);
    COMPUTE(0);
    __syncthreads();               // drains vmcnt: buf1 staged, buf0 free
    if (kt + 2 < nkt) STAGE(0, (kt + 2) * 64);
    COMPUTE(1);
    if (kt + 2 < nkt) __syncthreads();
  }
#undef STAGE
#undef COMPUTE

  // epilogue: C/D layout col=lane&15, row=(lane>>4)*4+j (m89/m91 verified)
#pragma unroll
  for (int mi = 0; mi < 4; ++mi) {
#pragma unroll
    for (int ni = 0; ni < 4; ++ni) {
      const long gc = bcol + wc + ni * 16 + (lane & 15);
      const long r0 = brow + wr + mi * 16 + (lane >> 4) * 4;
#pragma unroll
      for (int j = 0; j < 4; ++j) {
        const long r = r0 + j;
        const float v = acc[mi][ni][j];
        const long idx = r * (long)N + gc;
        if (EPI == 0) {
          const float hcv = bf2f(((const short*)aux)[idx]);
          const float g = 1.f / (1.f + __expf(-v));
          ((short*)outp)[idx] = f2bf(g * hcv);
        } else if (EPI == 1) {
          ((float*)outp)[idx] = ((const float*)aux)[idx] + v;
        } else if (EPI == 2) {
          const float x3 = v * v * v;
          const float z = 0.7978845608028654f * (v + 0.044715f * x3);
          const float th = 1.f - 2.f / (__expf(2.f * z) + 1.f);   // tanh(z)
          ((short*)outp)[idx] = f2bf(0.5f * v * (1.f + th));
        } else {
          ((float*)outp)[idx] += v;
        }
      }
    }
  }
}

// ---------- launch ----------
extern "C" void kernel_launch(void* const* d_in, const int* in_sizes, int n_in,
                              void* d_out, int out_size, void* d_ws, size_t ws_size,
                              hipStream_t stream) {
  const float* x      = (const float*)d_in[0];
  const float* ln1_w  = (const float*)d_in[1];
  const float* gate_w = (const float*)d_in[2];   // [512][512]
  const float* conv_w = (const float*)d_in[3];   // [512][17]
  const float* proj_w = (const float*)d_in[4];   // [512][512]
  const float* ln2_w  = (const float*)d_in[5];
  const float* mlp_w1 = (const float*)d_in[6];   // [512][2048]
  const float* mlp_w2 = (const float*)d_in[7];   // [2048][512]
  float* out = (float*)d_out;
  char* ws = (char*)d_ws;

  // workspace layout (bytes), all offsets 256B-aligned
  short* hn      = (short*)(ws + 0);                       // 64 MiB  (also hn2 later)
  short* hc      = (short*)(ws + 67108864L);               // 64 MiB  (hc, then u in-place)
  short* mid     = (short*)(ws + 134217728L);              // 256 MiB
  short* gate_wt = (short*)(ws + 402653184L);              // 512 KiB [512][512]
  short* proj_wt = (short*)(ws + 403177472L);              // 512 KiB
  short* w1t     = (short*)(ws + 403701760L);              // 2 MiB   [2048][512]
  short* w2t     = (short*)(ws + 405798912L);              // 2 MiB   [512][2048]
  float* convwT  = (float*)(ws + 407896064L);              // 34 KiB  [17][512]

  const dim3 b256(256);

  // weights -> bf16 transposed (per-call; deterministic, ~5 MB)
  wt_transpose<<<dim3(8, 8),  b256, 0, stream>>>(gate_w, gate_wt, 512, 512);
  wt_transpose<<<dim3(8, 8),  b256, 0, stream>>>(proj_w, proj_wt, 512, 512);
  wt_transpose<<<dim3(8, 32), b256, 0, stream>>>(mlp_w1, w1t, 512, 2048);
  wt_transpose<<<dim3(32, 8), b256, 0, stream>>>(mlp_w2, w2t, 2048, 512);
  convw_transpose<<<34, b256, 0, stream>>>(conv_w, convwT);

  // 1) hn = rmsnorm(x, ln1_w)
  rmsnorm_kernel<<<NTOK / 4, b256, 0, stream>>>(x, ln1_w, hn);
  // 2) hc = causal_dwconv(hn)
  dwconv_kernel<<<NTOK / 4, b256, 0, stream>>>(hn, convwT, hc);
  // 3) u = sigmoid(hn @ gate_w) * hc   (in-place into hc)
  gemm_bt<0><<<512 * 4, b256, 0, stream>>>(hn, gate_wt, 512, 512, 4, hc, hc);
  // 4) x2 = x + u @ proj_w  -> d_out (f32)
  gemm_bt<1><<<512 * 4, b256, 0, stream>>>(hc, proj_wt, 512, 512, 4, x, out);
  // 5) hn2 = rmsnorm(x2, ln2_w)  (reuse hn buffer)
  rmsnorm_kernel<<<NTOK / 4, b256, 0, stream>>>(out, ln2_w, hn);
  // 6) mid = gelu(hn2 @ mlp_w1)
  gemm_bt<2><<<512 * 16, b256, 0, stream>>>(hn, w1t, 512, 2048, 16, nullptr, mid);
  // 7) out += mid @ mlp_w2
  gemm_bt<3><<<512 * 4, b256, 0, stream>>>(mid, w2t, 2048, 512, 4, nullptr, out);
}

// Round 3
// 807.992 us; speedup vs baseline: 1.1389x; 1.1213x over previous
//
#include <hip/hip_runtime.h>
#include <hip/hip_bf16.h>
#include <cstdint>
#include <cstddef>

// ---------- types ----------
typedef __attribute__((ext_vector_type(8))) short short8;   // bf16 x8 (4 VGPRs)
typedef __attribute__((ext_vector_type(4))) short short4v;  // bf16 x4
typedef __attribute__((ext_vector_type(4))) float floatx4;

#define D_MODEL 512
#define HDIM    2048
#define TSEQ    16384
#define NTOK    65536   // B*T = 4*16384

// ---------- helpers ----------
__device__ __forceinline__ float bf2f(short s) {
  union { unsigned u; float f; } v; v.u = ((unsigned)(unsigned short)s) << 16; return v.f;
}
__device__ __forceinline__ short f2bf(float f) {
  union { float fv; unsigned u; } v; v.fv = f;
  unsigned u = v.u;
  u += 0x7FFFu + ((u >> 16) & 1u);   // RNE
  return (short)(u >> 16);
}
__device__ __forceinline__ void gload_lds16(const void* g, void* l) {
  // width=16 async global->LDS; LDS dest = wave-uniform base + lane*16 (m104)
  __builtin_amdgcn_global_load_lds((const __attribute__((address_space(1))) void*)g,
                                   (__attribute__((address_space(3))) void*)l, 16, 0, 0);
}

// ---------- weight convert + transpose: W[K][N] f32 -> Wt[N][K] bf16 ----------
__global__ void wt_transpose(const float* __restrict__ W, short* __restrict__ Wt,
                             const int K, const int N) {
  __shared__ float t[64][65];
  const int tid = threadIdx.x;
  const long k0 = (long)blockIdx.x * 64;
  const long n0 = (long)blockIdx.y * 64;
  const int rr = tid >> 4;
  const int cc = (tid & 15) * 4;
#pragma unroll
  for (int i = 0; i < 4; ++i) {
    const int r = rr + i * 16;
    const float4 v = *(const float4*)(W + (k0 + r) * N + n0 + cc);
    t[r][cc + 0] = v.x; t[r][cc + 1] = v.y; t[r][cc + 2] = v.z; t[r][cc + 3] = v.w;
  }
  __syncthreads();
#pragma unroll
  for (int i = 0; i < 4; ++i) {
    const int n = rr + i * 16;
    short4v o;
    o[0] = f2bf(t[cc + 0][n]);
    o[1] = f2bf(t[cc + 1][n]);
    o[2] = f2bf(t[cc + 2][n]);
    o[3] = f2bf(t[cc + 3][n]);
    *(short4v*)(Wt + (n0 + n) * K + k0 + cc) = o;
  }
}

// conv_w [512][17] f32 -> wT [17][512] f32
__global__ void convw_transpose(const float* __restrict__ cw, float* __restrict__ wT) {
  const int idx = blockIdx.x * 256 + threadIdx.x;
  if (idx >= 17 * D_MODEL) return;
  const int k = idx / D_MODEL;
  const int c = idx % D_MODEL;
  wT[idx] = cw[c * 17 + k];
}

// ---------- RMSNorm: one wave per row, f32 in -> bf16 out ----------
__global__ void rmsnorm_kernel(const float* __restrict__ x, const float* __restrict__ w,
                               short* __restrict__ outp) {
  const int lane = threadIdx.x & 63;
  const long row = (long)blockIdx.x * 4 + (threadIdx.x >> 6);
  const float* xr = x + row * D_MODEL + lane * 8;
  const float4 a = *(const float4*)xr;
  const float4 b = *(const float4*)(xr + 4);
  float ss = a.x * a.x + a.y * a.y + a.z * a.z + a.w * a.w
           + b.x * b.x + b.y * b.y + b.z * b.z + b.w * b.w;
#pragma unroll
  for (int m = 32; m; m >>= 1) ss += __shfl_xor(ss, m);
  const float scale = rsqrtf(ss * (1.0f / D_MODEL) + 1e-6f);
  const float4 wa = *(const float4*)(w + lane * 8);
  const float4 wb = *(const float4*)(w + lane * 8 + 4);
  short8 o;
  o[0] = f2bf(a.x * scale * wa.x);
  o[1] = f2bf(a.y * scale * wa.y);
  o[2] = f2bf(a.z * scale * wa.z);
  o[3] = f2bf(a.w * scale * wa.w);
  o[4] = f2bf(b.x * scale * wb.x);
  o[5] = f2bf(b.y * scale * wb.y);
  o[6] = f2bf(b.z * scale * wb.z);
  o[7] = f2bf(b.w * scale * wb.w);
  *(short8*)(outp + row * D_MODEL + lane * 8) = o;
}

// ---------- causal depthwise conv (K=17, dilation=1), bf16 in/out ----------
__global__ void dwconv_kernel(const short* __restrict__ hn, const float* __restrict__ wT,
                              short* __restrict__ hc) {
  const int tid = threadIdx.x;
  const int chunk = tid & 63;                       // 64 chunks of 8 channels
  const long row = (long)blockIdx.x * 4 + (tid >> 6);
  const int t = (int)(row & (TSEQ - 1));
  const int c0 = chunk * 8;
  float acc[8];
#pragma unroll
  for (int j = 0; j < 8; ++j) acc[j] = 0.f;
  const int kmin = (t >= 16) ? 0 : (16 - t);
  for (int k = kmin; k < 17; ++k) {
    const short8 h = *(const short8*)(hn + (row - 16 + k) * D_MODEL + c0);
    const float* wp = wT + k * D_MODEL + c0;
    const float4 w0 = *(const float4*)(wp);
    const float4 w1 = *(const float4*)(wp + 4);
    acc[0] += bf2f(h[0]) * w0.x;
    acc[1] += bf2f(h[1]) * w0.y;
    acc[2] += bf2f(h[2]) * w0.z;
    acc[3] += bf2f(h[3]) * w0.w;
    acc[4] += bf2f(h[4]) * w1.x;
    acc[5] += bf2f(h[5]) * w1.y;
    acc[6] += bf2f(h[6]) * w1.z;
    acc[7] += bf2f(h[7]) * w1.w;
  }
  short8 o;
#pragma unroll
  for (int j = 0; j < 8; ++j) o[j] = f2bf(acc[j]);
  *(short8*)(hc + row * D_MODEL + c0) = o;
}

// ---------- 256x256 8-phase GEMM: C[M][N] = A[M][K](bf16) x Bt[N][K](bf16) ----------
// 512 threads = 8 waves (2M x 4N). BK=64. LDS 128 KiB = 2 tile-buffers x (A 256x64 + B 256x64).
// Per K-tile: 4 phases, each {ds_read frags | stage 1 half-tile | barrier | lgkm0 |
// setprio(1) 16xMFMA setprio(0) | barrier}. Counted vmcnt(4) once per tile (q3), never 0
// in steady state (T3+T4). Stage schedule (derived waits, FIFO-verified):
//   prologue: B0(0),B1(0),A0(0),A1(0),B0(1),B1(1); tile t: q0->A0(t+1), q1->A1(t+1),
//   q2->B0(t+2), q3->B1(t+2). Boundary vmcnt(4) leaves exactly B0/B1(t+2) in flight.
// WAR: each slot's stage issue is >=1 closing-barrier after its occupant's last ds_read.
// Both-sides XOR chunk swizzle (linear LDS dest for global_load_lds + pre-swizzled
// global source + swizzled ds_read) -> 0 bank conflicts (verified R1/R2).
#define PHASE_BAR() __builtin_amdgcn_s_barrier()
#define LGKM0() { asm volatile("s_waitcnt lgkmcnt(0)" ::: "memory"); __builtin_amdgcn_sched_barrier(0); }
#define VMC4()  { asm volatile("s_waitcnt vmcnt(4)" ::: "memory"); __builtin_amdgcn_sched_barrier(0); }
#define VMC0()  { asm volatile("s_waitcnt vmcnt(0)" ::: "memory"); __builtin_amdgcn_sched_barrier(0); }

template <int EPI>
__global__ __launch_bounds__(512, 2)
void gemm256(const short* __restrict__ A, const short* __restrict__ Bt,
             const int K, const int N, const int nbn,
             const void* __restrict__ aux, void* __restrict__ outp) {
  __shared__ short Alds[2 * 2 * 128 * 64];   // [buf][half][row 128][k 64]
  __shared__ short Blds[2 * 2 * 128 * 64];
  const int tid = threadIdx.x;
  const int lane = tid & 63;
  const int w = tid >> 6;
  const int wm = w >> 2;          // 0..1  (M half of block)
  const int wn = w & 3;           // 0..3  (N quarter of block)

  // XCD-chunked swizzle (all call sites have gridDim.x % 8 == 0)
  const int nwg = gridDim.x;
  const int cpx = nwg >> 3;
  const int bid = blockIdx.x;
  const int wid = (bid & 7) * cpx + (bid >> 3);
  const long brow = (long)(wid / nbn) * 256;
  const long bcol = (long)(wid % nbn) * 256;

  floatx4 acc[8][4];
#pragma unroll
  for (int i = 0; i < 8; ++i)
#pragma unroll
    for (int j = 0; j < 4; ++j) acc[i][j] = {0.f, 0.f, 0.f, 0.f};

  short8 af[4][2];   // A frags: 4 m-frags x 2 k-slices (m0-3 then m4-7)
  short8 bfr[4][2];  // B frags: 4 n-frags x 2 k-slices (whole tile, held in regs)

  // staging addresses: pre-swizzled global chunk, linear LDS dest
  const int chunkx = (lane & 7) ^ (lane >> 3);
  const short* gA = A + (brow + w * 8 + (lane >> 3)) * (long)K + chunkx * 8;
  const short* gB = Bt + (bcol + w * 8 + (lane >> 3)) * (long)K + chunkx * 8;
  const int kchunk = lane >> 4;   // 0..3

#define STGA(half, BUF, koff)                                                  \
  { _Pragma("unroll")                                                          \
    for (int j = 0; j < 2; ++j)                                                \
      gload_lds16(gA + ((half) * 128 + j * 64) * (long)K + (koff),             \
                  &Alds[(((BUF) * 2 + (half)) * 128 + j * 64 + w * 8) * 64]); }
#define STGB(half, BUF, koff)                                                  \
  { _Pragma("unroll")                                                          \
    for (int j = 0; j < 2; ++j)                                                \
      gload_lds16(gB + ((half) * 128 + j * 64) * (long)K + (koff),             \
                  &Blds[(((BUF) * 2 + (half)) * 128 + j * 64 + w * 8) * 64]); }

#define LDA4(mbase, BUF)                                                       \
  { _Pragma("unroll")                                                          \
    for (int mi = 0; mi < 4; ++mi)                                             \
      _Pragma("unroll")                                                        \
      for (int ks = 0; ks < 2; ++ks) {                                         \
        const int r = ((mbase) + mi) * 16 + (lane & 15);                       \
        const int c = (ks * 4 + kchunk) ^ (r & 7);                             \
        af[mi][ks] = *(const short8*)(&Alds[(((BUF) * 2 + wm) * 128 + r) * 64 + c * 8]); \
      } }
#define LDB2(nbase, BUF)                                                       \
  { _Pragma("unroll")                                                          \
    for (int nn = 0; nn < 2; ++nn)                                             \
      _Pragma("unroll")                                                        \
      for (int ks = 0; ks < 2; ++ks) {                                         \
        const int r = (wn & 1) * 64 + ((nbase) + nn) * 16 + (lane & 15);       \
        const int c = (ks * 4 + kchunk) ^ (r & 7);                             \
        bfr[(nbase) + nn][ks] = *(const short8*)(&Blds[(((BUF) * 2 + (wn >> 1)) * 128 + r) * 64 + c * 8]); \
      } }

#define MMACL(mbase, nbase)                                                    \
  { __builtin_amdgcn_s_setprio(1);                                             \
    _Pragma("unroll")                                                          \
    for (int mi = 0; mi < 4; ++mi)                                             \
      _Pragma("unroll")                                                        \
      for (int nn = 0; nn < 2; ++nn)                                           \
        _Pragma("unroll")                                                      \
        for (int ks = 0; ks < 2; ++ks)                                         \
          acc[(mbase) + mi][(nbase) + nn] = __builtin_amdgcn_mfma_f32_16x16x32_bf16( \
              af[mi][ks], bfr[(nbase) + nn][ks], acc[(mbase) + mi][(nbase) + nn], 0, 0, 0); \
    __builtin_amdgcn_s_setprio(0); }

  // TILE: DOST01 stages A0/A1(t+1) at q0/q1; DOST23 stages B0/B1(t+2) at q2/q3.
#define TILE(BUF, DOST01, DOST23, W4, W0, kA, kB)                              \
  {                                                                            \
    /* q0 */                                                                   \
    LDA4(0, BUF); LDB2(0, BUF);                                                \
    if (DOST01) STGA(0, (BUF) ^ 1, kA);                                        \
    PHASE_BAR(); LGKM0(); MMACL(0, 0); PHASE_BAR();                            \
    /* q1 */                                                                   \
    LDB2(2, BUF);                                                              \
    if (DOST01) STGA(1, (BUF) ^ 1, kA);                                        \
    PHASE_BAR(); LGKM0(); MMACL(0, 2); PHASE_BAR();                            \
    /* q2 */                                                                   \
    LDA4(4, BUF);                                                              \
    if (DOST23) STGB(0, BUF, kB);                                              \
    PHASE_BAR(); LGKM0(); MMACL(4, 0); PHASE_BAR();                            \
    /* q3 */                                                                   \
    if (DOST23) STGB(1, BUF, kB);                                              \
    if (W4) VMC4();                                                            \
    if (W0) VMC0();                                                            \
    PHASE_BAR(); MMACL(4, 2); PHASE_BAR();                                     \
  }

  // prologue: stream order B0(0),B1(0),A0(0),A1(0),B0(1),B1(1); leave tile1 B's in flight
  STGB(0, 0, 0); STGB(1, 0, 0); STGA(0, 0, 0); STGA(1, 0, 0);
  STGB(0, 1, 64); STGB(1, 1, 64);
  VMC4(); PHASE_BAR();

  const int nkt = K >> 6;          // 8 or 32 at our call sites (even, >= 8)
  int kA = 64, kB = 128;
  for (int t = 0; t < nkt - 2; t += 2) {
    TILE(0, 1, 1, 1, 0, kA, kB); kA += 64; kB += 64;
    TILE(1, 1, 1, 1, 0, kA, kB); kA += 64; kB += 64;
  }
  TILE(0, 1, 0, 0, 1, kA, 0);      // tile nkt-2: stage A(nkt-1) only, then full drain
  TILE(1, 0, 0, 0, 0, 0, 0);       // tile nkt-1: pure compute

#undef TILE
#undef MMACL
#undef LDA4
#undef LDB2
#undef STGA
#undef STGB

  // epilogue: C/D layout col=lane&15, row=(lane>>4)*4+j (verified R1/R2)
#pragma unroll
  for (int mi = 0; mi < 8; ++mi) {
#pragma unroll
    for (int ni = 0; ni < 4; ++ni) {
      const long gc = bcol + wn * 64 + ni * 16 + (lane & 15);
      const long r0 = brow + wm * 128 + mi * 16 + (lane >> 4) * 4;
#pragma unroll
      for (int j = 0; j < 4; ++j) {
        const long r = r0 + j;
        const float v = acc[mi][ni][j];
        const long idx = r * (long)N + gc;
        if (EPI == 0) {
          const float hcv = bf2f(((const short*)aux)[idx]);
          const float g = 1.f / (1.f + __expf(-v));
          ((short*)outp)[idx] = f2bf(g * hcv);
        } else if (EPI == 1) {
          ((float*)outp)[idx] = ((const float*)aux)[idx] + v;
        } else if (EPI == 2) {
          const float x3 = v * v * v;
          const float z = 0.7978845608028654f * (v + 0.044715f * x3);
          const float th = 1.f - 2.f / (__expf(2.f * z) + 1.f);   // tanh(z)
          ((short*)outp)[idx] = f2bf(0.5f * v * (1.f + th));
        } else {
          ((float*)outp)[idx] += v;
        }
      }
    }
  }
}

// ---------- launch ----------
extern "C" void kernel_launch(void* const* d_in, const int* in_sizes, int n_in,
                              void* d_out, int out_size, void* d_ws, size_t ws_size,
                              hipStream_t stream) {
  const float* x      = (const float*)d_in[0];
  const float* ln1_w  = (const float*)d_in[1];
  const float* gate_w = (const float*)d_in[2];   // [512][512]
  const float* conv_w = (const float*)d_in[3];   // [512][17]
  const float* proj_w = (const float*)d_in[4];   // [512][512]
  const float* ln2_w  = (const float*)d_in[5];
  const float* mlp_w1 = (const float*)d_in[6];   // [512][2048]
  const float* mlp_w2 = (const float*)d_in[7];   // [2048][512]
  float* out = (float*)d_out;
  char* ws = (char*)d_ws;

  // workspace layout (bytes), all offsets 256B-aligned
  short* hn      = (short*)(ws + 0);                       // 64 MiB  (also hn2 later)
  short* hc      = (short*)(ws + 67108864L);               // 64 MiB  (hc, then u in-place)
  short* mid     = (short*)(ws + 134217728L);              // 256 MiB
  short* gate_wt = (short*)(ws + 402653184L);              // 512 KiB [512][512]
  short* proj_wt = (short*)(ws + 403177472L);              // 512 KiB
  short* w1t     = (short*)(ws + 403701760L);              // 2 MiB   [2048][512]
  short* w2t     = (short*)(ws + 405798912L);              // 2 MiB   [512][2048]
  float* convwT  = (float*)(ws + 407896064L);              // 34 KiB  [17][512]

  const dim3 b256(256);
  const dim3 b512(512);

  // weights -> bf16 transposed (per-call; deterministic, ~5 MB)
  wt_transpose<<<dim3(8, 8),  b256, 0, stream>>>(gate_w, gate_wt, 512, 512);
  wt_transpose<<<dim3(8, 8),  b256, 0, stream>>>(proj_w, proj_wt, 512, 512);
  wt_transpose<<<dim3(8, 32), b256, 0, stream>>>(mlp_w1, w1t, 512, 2048);
  wt_transpose<<<dim3(32, 8), b256, 0, stream>>>(mlp_w2, w2t, 2048, 512);
  convw_transpose<<<34, b256, 0, stream>>>(conv_w, convwT);

  // 1) hn = rmsnorm(x, ln1_w)
  rmsnorm_kernel<<<NTOK / 4, b256, 0, stream>>>(x, ln1_w, hn);
  // 2) hc = causal_dwconv(hn)
  dwconv_kernel<<<NTOK / 4, b256, 0, stream>>>(hn, convwT, hc);
  // 3) u = sigmoid(hn @ gate_w) * hc   (in-place into hc)
  gemm256<0><<<256 * 2, b512, 0, stream>>>(hn, gate_wt, 512, 512, 2, hc, hc);
  // 4) x2 = x + u @ proj_w  -> d_out (f32)
  gemm256<1><<<256 * 2, b512, 0, stream>>>(hc, proj_wt, 512, 512, 2, x, out);
  // 5) hn2 = rmsnorm(x2, ln2_w)  (reuse hn buffer)
  rmsnorm_kernel<<<NTOK / 4, b256, 0, stream>>>(out, ln2_w, hn);
  // 6) mid = gelu(hn2 @ mlp_w1)
  gemm256<2><<<256 * 8, b512, 0, stream>>>(hn, w1t, 512, 2048, 8, nullptr, mid);
  // 7) out += mid @ mlp_w2
  gemm256<3><<<256 * 2, b512, 0, stream>>>(mid, w2t, 2048, 512, 2, nullptr, out);
}

// Round 4
// 695.904 us; speedup vs baseline: 1.3224x; 1.1611x over previous
//
#include <hip/hip_runtime.h>
#include <hip/hip_bf16.h>
#include <cstdint>
#include <cstddef>

// ---------- types ----------
typedef __attribute__((ext_vector_type(8))) short short8;   // bf16 x8 (4 VGPRs)
typedef __attribute__((ext_vector_type(4))) short short4v;  // bf16 x4
typedef __attribute__((ext_vector_type(4))) float floatx4;

#define D_MODEL 512
#define HDIM    2048
#define TSEQ    16384
#define NTOK    65536   // B*T = 4*16384

// ---------- helpers ----------
__device__ __forceinline__ float bf2f(short s) {
  union { unsigned u; float f; } v; v.u = ((unsigned)(unsigned short)s) << 16; return v.f;
}
__device__ __forceinline__ short f2bf(float f) {
  union { float fv; unsigned u; } v; v.fv = f;
  unsigned u = v.u;
  u += 0x7FFFu + ((u >> 16) & 1u);   // RNE
  return (short)(u >> 16);
}
__device__ __forceinline__ void gload_lds16(const void* g, void* l) {
  // width=16 async global->LDS; LDS dest = wave-uniform base + lane*16 (m104)
  __builtin_amdgcn_global_load_lds((const __attribute__((address_space(1))) void*)g,
                                   (__attribute__((address_space(3))) void*)l, 16, 0, 0);
}

// ---------- weight convert + transpose: W[K][N] f32 -> Wt[N][K] bf16 ----------
__global__ void wt_transpose(const float* __restrict__ W, short* __restrict__ Wt,
                             const int K, const int N) {
  __shared__ float t[64][65];
  const int tid = threadIdx.x;
  const long k0 = (long)blockIdx.x * 64;
  const long n0 = (long)blockIdx.y * 64;
  const int rr = tid >> 4;
  const int cc = (tid & 15) * 4;
#pragma unroll
  for (int i = 0; i < 4; ++i) {
    const int r = rr + i * 16;
    const float4 v = *(const float4*)(W + (k0 + r) * N + n0 + cc);
    t[r][cc + 0] = v.x; t[r][cc + 1] = v.y; t[r][cc + 2] = v.z; t[r][cc + 3] = v.w;
  }
  __syncthreads();
#pragma unroll
  for (int i = 0; i < 4; ++i) {
    const int n = rr + i * 16;
    short4v o;
    o[0] = f2bf(t[cc + 0][n]);
    o[1] = f2bf(t[cc + 1][n]);
    o[2] = f2bf(t[cc + 2][n]);
    o[3] = f2bf(t[cc + 3][n]);
    *(short4v*)(Wt + (n0 + n) * K + k0 + cc) = o;
  }
}

// conv_w [512][17] f32 -> wT [17][512] f32
__global__ void convw_transpose(const float* __restrict__ cw, float* __restrict__ wT) {
  const int idx = blockIdx.x * 256 + threadIdx.x;
  if (idx >= 17 * D_MODEL) return;
  const int k = idx / D_MODEL;
  const int c = idx % D_MODEL;
  wT[idx] = cw[c * 17 + k];
}

// ---------- RMSNorm: one wave per row, f32 in -> bf16 out ----------
__global__ void rmsnorm_kernel(const float* __restrict__ x, const float* __restrict__ w,
                               short* __restrict__ outp) {
  const int lane = threadIdx.x & 63;
  const long row = (long)blockIdx.x * 4 + (threadIdx.x >> 6);
  const float* xr = x + row * D_MODEL + lane * 8;
  const float4 a = *(const float4*)xr;
  const float4 b = *(const float4*)(xr + 4);
  float ss = a.x * a.x + a.y * a.y + a.z * a.z + a.w * a.w
           + b.x * b.x + b.y * b.y + b.z * b.z + b.w * b.w;
#pragma unroll
  for (int m = 32; m; m >>= 1) ss += __shfl_xor(ss, m);
  const float scale = rsqrtf(ss * (1.0f / D_MODEL) + 1e-6f);
  const float4 wa = *(const float4*)(w + lane * 8);
  const float4 wb = *(const float4*)(w + lane * 8 + 4);
  short8 o;
  o[0] = f2bf(a.x * scale * wa.x);
  o[1] = f2bf(a.y * scale * wa.y);
  o[2] = f2bf(a.z * scale * wa.z);
  o[3] = f2bf(a.w * scale * wa.w);
  o[4] = f2bf(b.x * scale * wb.x);
  o[5] = f2bf(b.y * scale * wb.y);
  o[6] = f2bf(b.z * scale * wb.z);
  o[7] = f2bf(b.w * scale * wb.w);
  *(short8*)(outp + row * D_MODEL + lane * 8) = o;
}

// ---------- causal depthwise conv (K=17, dilation=1), bf16 in/out ----------
__global__ void dwconv_kernel(const short* __restrict__ hn, const float* __restrict__ wT,
                              short* __restrict__ hc) {
  const int tid = threadIdx.x;
  const int chunk = tid & 63;                       // 64 chunks of 8 channels
  const long row = (long)blockIdx.x * 4 + (tid >> 6);
  const int t = (int)(row & (TSEQ - 1));
  const int c0 = chunk * 8;
  float acc[8];
#pragma unroll
  for (int j = 0; j < 8; ++j) acc[j] = 0.f;
  const int kmin = (t >= 16) ? 0 : (16 - t);
  for (int k = kmin; k < 17; ++k) {
    const short8 h = *(const short8*)(hn + (row - 16 + k) * D_MODEL + c0);
    const float* wp = wT + k * D_MODEL + c0;
    const float4 w0 = *(const float4*)(wp);
    const float4 w1 = *(const float4*)(wp + 4);
    acc[0] += bf2f(h[0]) * w0.x;
    acc[1] += bf2f(h[1]) * w0.y;
    acc[2] += bf2f(h[2]) * w0.z;
    acc[3] += bf2f(h[3]) * w0.w;
    acc[4] += bf2f(h[4]) * w1.x;
    acc[5] += bf2f(h[5]) * w1.y;
    acc[6] += bf2f(h[6]) * w1.z;
    acc[7] += bf2f(h[7]) * w1.w;
  }
  short8 o;
#pragma unroll
  for (int j = 0; j < 8; ++j) o[j] = f2bf(acc[j]);
  *(short8*)(hc + row * D_MODEL + c0) = o;
}

// ---------- 256x256 8-phase GEMM: C[M][N] = A[M][K](bf16) x Bt[N][K](bf16) ----------
// 512 threads = 8 waves (2M x 4N). BK=64. LDS 128 KiB = 2 tile-buffers x (A 256x64 + B 256x64).
// Fragment reads are INLINE-ASM ds_read_b128 (base VGPR + offset:imm) so the compiler's
// LDS-DMA alias tracking cannot insert conservative vmcnt(0) drains before them — the
// counted-vmcnt pipeline (T4) stays intact. Manual lgkmcnt(0)+sched_barrier(0) before
// each MFMA cluster (rule #18). vmcnt(4) once per tile, AFTER q3's MFMA cluster.
// Stage schedule (FIFO-verified): prologue B0(0),B1(0),A0(0),A1(0),B0(1),B1(1);
// tile t: q0->A0(t+1), q1->A1(t+1), q2->B0(t+2), q3->B1(t+2); vmcnt(4)@q3 leaves
// exactly B0/B1(t+2) in flight. Both-sides XOR chunk swizzle -> 0 bank conflicts (R1-R3).
#define PHASE_BAR() __builtin_amdgcn_s_barrier()
#define LGKM0() { asm volatile("s_waitcnt lgkmcnt(0)" ::: "memory"); __builtin_amdgcn_sched_barrier(0); }
#define VMC4()  { asm volatile("s_waitcnt vmcnt(4)" ::: "memory"); __builtin_amdgcn_sched_barrier(0); }
#define VMC0()  { asm volatile("s_waitcnt vmcnt(0)" ::: "memory"); __builtin_amdgcn_sched_barrier(0); }
// asm ds_read_b128: dst 4-VGPR tuple, addr VGPR, literal byte offset
#define DSR1(dst, addr, imm) \
  asm volatile("ds_read_b128 %0, %1 offset:%2" : "=v"(dst) : "v"(addr), "i"(imm))

template <int EPI>
__global__ __launch_bounds__(512, 2)
void gemm256(const short* __restrict__ A, const short* __restrict__ Bt,
             const int K, const int N, const int nbn,
             const void* __restrict__ aux, void* __restrict__ outp) {
  __shared__ short Alds[2 * 2 * 128 * 64];   // [buf][half][row 128][k 64]
  __shared__ short Blds[2 * 2 * 128 * 64];
  const int tid = threadIdx.x;
  const int lane = tid & 63;
  const int w = tid >> 6;
  const int wm = w >> 2;          // 0..1  (M half of block)
  const int wn = w & 3;           // 0..3  (N quarter of block)

  // XCD-chunked swizzle (all call sites have gridDim.x % 8 == 0)
  const int nwg = gridDim.x;
  const int cpx = nwg >> 3;
  const int bid = blockIdx.x;
  const int wid = (bid & 7) * cpx + (bid >> 3);
  const long brow = (long)(wid / nbn) * 256;
  const long bcol = (long)(wid % nbn) * 256;

  floatx4 acc[8][4];
#pragma unroll
  for (int i = 0; i < 8; ++i)
#pragma unroll
    for (int j = 0; j < 4; ++j) acc[i][j] = {0.f, 0.f, 0.f, 0.f};

  short8 af[4][2];   // A frags: 4 m-frags x 2 k-slices (rows mbase..mbase+3)
  short8 bfr[4][2];  // B frags: 4 n-frags x 2 k-slices (whole tile, held in regs)

  // staging addresses: pre-swizzled global chunk, linear LDS dest
  const int chunkx = (lane & 7) ^ (lane >> 3);
  const short* gA = A + (brow + w * 8 + (lane >> 3)) * (long)K + chunkx * 8;
  const short* gB = Bt + (bcol + w * 8 + (lane >> 3)) * (long)K + chunkx * 8;
  const int kchunk = lane >> 4;   // 0..3

  // ds_read base addresses (LDS byte offsets, wave/lane-invariant across K-loop).
  // A frag byte = (BUF*2+wm)*16384 + r*128 + c*16,  r=(mbase+mi)*16+(lane&15),
  //   c=(ks*4+kchunk)^(lane&7)  [r&7 == lane&7 since 16-multiples vanish mod 8]
  // -> addr = Abase + wm*16384 + (lane&15)*128 + c(ks)*16 ; imm = BUF*32768+(mbase+mi)*2048
  const unsigned Abase = (unsigned)(uintptr_t)(__attribute__((address_space(3))) short*)Alds;
  const unsigned Bbase = (unsigned)(uintptr_t)(__attribute__((address_space(3))) short*)Blds;
  const unsigned lanelo = (unsigned)((lane & 15) * 128);
  const unsigned c0t = (unsigned)(((0 + kchunk) ^ (lane & 7)) * 16);
  const unsigned c1t = (unsigned)(((4 + kchunk) ^ (lane & 7)) * 16);
  const unsigned adrA0 = Abase + (unsigned)(wm * 16384) + lanelo + c0t;
  const unsigned adrA1 = Abase + (unsigned)(wm * 16384) + lanelo + c1t;
  const unsigned adrB0 = Bbase + (unsigned)((wn >> 1) * 16384 + (wn & 1) * 8192) + lanelo + c0t;
  const unsigned adrB1 = Bbase + (unsigned)((wn >> 1) * 16384 + (wn & 1) * 8192) + lanelo + c1t;

#define STGA(half, BUF, koff)                                                  \
  { _Pragma("unroll")                                                          \
    for (int j = 0; j < 2; ++j)                                                \
      gload_lds16(gA + ((half) * 128 + j * 64) * (long)K + (koff),             \
                  &Alds[(((BUF) * 2 + (half)) * 128 + j * 64 + w * 8) * 64]); }
#define STGB(half, BUF, koff)                                                  \
  { _Pragma("unroll")                                                          \
    for (int j = 0; j < 2; ++j)                                                \
      gload_lds16(gB + ((half) * 128 + j * 64) * (long)K + (koff),             \
                  &Blds[(((BUF) * 2 + (half)) * 128 + j * 64 + w * 8) * 64]); }

#define LDA4(mbase, BUF) {                                                     \
    DSR1(af[0][0], adrA0, (BUF)*32768 + ((mbase)+0)*2048);                     \
    DSR1(af[0][1], adrA1, (BUF)*32768 + ((mbase)+0)*2048);                     \
    DSR1(af[1][0], adrA0, (BUF)*32768 + ((mbase)+1)*2048);                     \
    DSR1(af[1][1], adrA1, (BUF)*32768 + ((mbase)+1)*2048);                     \
    DSR1(af[2][0], adrA0, (BUF)*32768 + ((mbase)+2)*2048);                     \
    DSR1(af[2][1], adrA1, (BUF)*32768 + ((mbase)+2)*2048);                     \
    DSR1(af[3][0], adrA0, (BUF)*32768 + ((mbase)+3)*2048);                     \
    DSR1(af[3][1], adrA1, (BUF)*32768 + ((mbase)+3)*2048); }
#define LDB2(nbase, BUF) {                                                     \
    DSR1(bfr[(nbase)+0][0], adrB0, (BUF)*32768 + ((nbase)+0)*2048);            \
    DSR1(bfr[(nbase)+0][1], adrB1, (BUF)*32768 + ((nbase)+0)*2048);            \
    DSR1(bfr[(nbase)+1][0], adrB0, (BUF)*32768 + ((nbase)+1)*2048);            \
    DSR1(bfr[(nbase)+1][1], adrB1, (BUF)*32768 + ((nbase)+1)*2048); }

#define MMACL(mbase, nbase)                                                    \
  { __builtin_amdgcn_s_setprio(1);                                             \
    _Pragma("unroll")                                                          \
    for (int mi = 0; mi < 4; ++mi)                                             \
      _Pragma("unroll")                                                        \
      for (int nn = 0; nn < 2; ++nn)                                           \
        _Pragma("unroll")                                                      \
        for (int ks = 0; ks < 2; ++ks)                                         \
          acc[(mbase) + mi][(nbase) + nn] = __builtin_amdgcn_mfma_f32_16x16x32_bf16( \
              af[mi][ks], bfr[(nbase) + nn][ks], acc[(mbase) + mi][(nbase) + nn], 0, 0, 0); \
    __builtin_amdgcn_s_setprio(0); }

  // TILE: DOST01 stages A0/A1(t+1) at q0/q1; DOST23 stages B0/B1(t+2) at q2/q3.
  // Per-tile vmcnt AFTER q3's MFMA cluster (wait overlapped by compute).
#define TILE(BUF, DOST01, DOST23, W4, W0, kA, kB)                              \
  {                                                                            \
    /* q0 */                                                                   \
    LDA4(0, BUF); LDB2(0, BUF);                                                \
    if (DOST01) STGA(0, (BUF) ^ 1, kA);                                        \
    PHASE_BAR(); LGKM0(); MMACL(0, 0); PHASE_BAR();                            \
    /* q1 */                                                                   \
    LDB2(2, BUF);                                                              \
    if (DOST01) STGA(1, (BUF) ^ 1, kA);                                        \
    PHASE_BAR(); LGKM0(); MMACL(0, 2); PHASE_BAR();                            \
    /* q2 */                                                                   \
    LDA4(4, BUF);                                                              \
    if (DOST23) STGB(0, BUF, kB);                                              \
    PHASE_BAR(); LGKM0(); MMACL(4, 0); PHASE_BAR();                            \
    /* q3 */                                                                   \
    if (DOST23) STGB(1, BUF, kB);                                              \
    PHASE_BAR(); MMACL(4, 2);                                                  \
    if (W4) VMC4();                                                            \
    if (W0) VMC0();                                                            \
    PHASE_BAR();                                                               \
  }

  // prologue: stream order B0(0),B1(0),A0(0),A1(0),B0(1),B1(1); leave tile1 B's in flight
  STGB(0, 0, 0); STGB(1, 0, 0); STGA(0, 0, 0); STGA(1, 0, 0);
  STGB(0, 1, 64); STGB(1, 1, 64);
  VMC4(); PHASE_BAR();

  const int nkt = K >> 6;          // 8 or 32 at our call sites (even, >= 8)
  int kA = 64, kB = 128;
  for (int t = 0; t < nkt - 2; t += 2) {
    TILE(0, 1, 1, 1, 0, kA, kB); kA += 64; kB += 64;
    TILE(1, 1, 1, 1, 0, kA, kB); kA += 64; kB += 64;
  }
  TILE(0, 1, 0, 0, 1, kA, 0);      // tile nkt-2: stage A(nkt-1) only, then full drain
  TILE(1, 0, 0, 0, 0, 0, 0);       // tile nkt-1: pure compute

#undef TILE
#undef MMACL
#undef LDA4
#undef LDB2
#undef STGA
#undef STGB

  // epilogue: C/D layout col=lane&15, row=(lane>>4)*4+j. 32-bit index math
  // (max idx = 65536*2048 < 2^31) to kill 64-bit mul chains.
#pragma unroll
  for (int mi = 0; mi < 8; ++mi) {
    const int r0 = (int)brow + wm * 128 + mi * 16 + (lane >> 4) * 4;
#pragma unroll
    for (int j = 0; j < 4; ++j) {
      const int rb = (r0 + j) * N;
      const int gcb = (int)bcol + wn * 64 + (lane & 15);
#pragma unroll
      for (int ni = 0; ni < 4; ++ni) {
        const int idx = rb + gcb + ni * 16;
        const float v = acc[mi][ni][j];
        if (EPI == 0) {
          const float hcv = bf2f(((const short*)aux)[idx]);
          const float g = 1.f / (1.f + __expf(-v));
          ((short*)outp)[idx] = f2bf(g * hcv);
        } else if (EPI == 1) {
          ((float*)outp)[idx] = ((const float*)aux)[idx] + v;
        } else if (EPI == 2) {
          const float x3 = v * v * v;
          const float z = 0.7978845608028654f * (v + 0.044715f * x3);
          const float th = 1.f - 2.f / (__expf(2.f * z) + 1.f);   // tanh(z)
          ((short*)outp)[idx] = f2bf(0.5f * v * (1.f + th));
        } else {
          ((float*)outp)[idx] += v;
        }
      }
    }
  }
}

// ---------- launch ----------
extern "C" void kernel_launch(void* const* d_in, const int* in_sizes, int n_in,
                              void* d_out, int out_size, void* d_ws, size_t ws_size,
                              hipStream_t stream) {
  const float* x      = (const float*)d_in[0];
  const float* ln1_w  = (const float*)d_in[1];
  const float* gate_w = (const float*)d_in[2];   // [512][512]
  const float* conv_w = (const float*)d_in[3];   // [512][17]
  const float* proj_w = (const float*)d_in[4];   // [512][512]
  const float* ln2_w  = (const float*)d_in[5];
  const float* mlp_w1 = (const float*)d_in[6];   // [512][2048]
  const float* mlp_w2 = (const float*)d_in[7];   // [2048][512]
  float* out = (float*)d_out;
  char* ws = (char*)d_ws;

  // workspace layout (bytes), all offsets 256B-aligned
  short* hn      = (short*)(ws + 0);                       // 64 MiB  (also hn2 later)
  short* hc      = (short*)(ws + 67108864L);               // 64 MiB  (hc, then u in-place)
  short* mid     = (short*)(ws + 134217728L);              // 256 MiB
  short* gate_wt = (short*)(ws + 402653184L);              // 512 KiB [512][512]
  short* proj_wt = (short*)(ws + 403177472L);              // 512 KiB
  short* w1t     = (short*)(ws + 403701760L);              // 2 MiB   [2048][512]
  short* w2t     = (short*)(ws + 405798912L);              // 2 MiB   [512][2048]
  float* convwT  = (float*)(ws + 407896064L);              // 34 KiB  [17][512]

  const dim3 b256(256);
  const dim3 b512(512);

  // weights -> bf16 transposed (per-call; deterministic, ~5 MB)
  wt_transpose<<<dim3(8, 8),  b256, 0, stream>>>(gate_w, gate_wt, 512, 512);
  wt_transpose<<<dim3(8, 8),  b256, 0, stream>>>(proj_w, proj_wt, 512, 512);
  wt_transpose<<<dim3(8, 32), b256, 0, stream>>>(mlp_w1, w1t, 512, 2048);
  wt_transpose<<<dim3(32, 8), b256, 0, stream>>>(mlp_w2, w2t, 2048, 512);
  convw_transpose<<<34, b256, 0, stream>>>(conv_w, convwT);

  // 1) hn = rmsnorm(x, ln1_w)
  rmsnorm_kernel<<<NTOK / 4, b256, 0, stream>>>(x, ln1_w, hn);
  // 2) hc = causal_dwconv(hn)
  dwconv_kernel<<<NTOK / 4, b256, 0, stream>>>(hn, convwT, hc);
  // 3) u = sigmoid(hn @ gate_w) * hc   (in-place into hc)
  gemm256<0><<<256 * 2, b512, 0, stream>>>(hn, gate_wt, 512, 512, 2, hc, hc);
  // 4) x2 = x + u @ proj_w  -> d_out (f32)
  gemm256<1><<<256 * 2, b512, 0, stream>>>(hc, proj_wt, 512, 512, 2, x, out);
  // 5) hn2 = rmsnorm(x2, ln2_w)  (reuse hn buffer)
  rmsnorm_kernel<<<NTOK / 4, b256, 0, stream>>>(out, ln2_w, hn);
  // 6) mid = gelu(hn2 @ mlp_w1)
  gemm256<2><<<256 * 8, b512, 0, stream>>>(hn, w1t, 512, 2048, 8, nullptr, mid);
  // 7) out += mid @ mlp_w2
  gemm256<3><<<256 * 2, b512, 0, stream>>>(mid, w2t, 2048, 512, 2, nullptr, out);
}